// Round 12
// baseline (33.836 us; speedup 1.0000x reference)
//
#include <hip/hip_runtime.h>
#include <hip/hip_bf16.h>

// R23 = R21 (verified 33.06us champion) + two safe trims + builtin-permlane.
// R22 post-mortem (absmax 2.98): hand-asm permlane lacked the VALU->cross-lane
// hazard wait-states (s_nop) that the COMPILER inserts for builtins; inside
// asm volatile they were my job and were missing -> permlane read stale regs.
// Value-level math was correct. So:
// - permlane16/32_swap via OFFICIAL __builtin_amdgcn_permlane*_swap
//   (returns uint2 {a',b'}; fmax(a',b') == fmax(x, shfl_xor(x,16/32)) exactly
//   -> bit-identical m_run), guarded by __has_builtin with __shfl_xor
//   fallback (zero risk if builtin absent).
// - Trim A (safe, from R22): first QK MFMA per fragment takes persistent Z4
//   as C-operand -> no 16x v_mov sacc init per tile.
// - Trim B (safe, from R22): exp2->cvt->PV fused per kblk (p[4][4] dropped).
// Everything else R21-verbatim: 8 waves x 16 q-rows, ONE barrier/tile,
// unroll-2 literal bs, hoisted off8, in-place mask, v_max3 tree, staging,
// swizzles, rounding, MFMA order.

#define NB    64
#define LQ    1024
#define LK    1024
#define DH    64
#define KVT   64
#define QT    128
#define NITEMS (NB * (LQ / QT))      // 512
#define NEGF  1.0e30f
#define SC2   0.18033688011112042f   // 0.125 * log2(e)
#define THR   8.0f                   // defer-max threshold (log2 units)

typedef __attribute__((ext_vector_type(8))) short    bf8;
typedef __attribute__((ext_vector_type(8))) ushort   u16x8;
typedef __attribute__((ext_vector_type(4))) ushort   u16x4;
typedef __attribute__((ext_vector_type(4))) float    f4;
typedef __attribute__((ext_vector_type(2))) unsigned u32x2;

#if defined(__has_builtin)
#if __has_builtin(__builtin_amdgcn_permlane16_swap) && __has_builtin(__builtin_amdgcn_permlane32_swap)
#define HAVE_PLSWAP 1
#endif
#endif

__device__ __forceinline__ ushort2 cvt2(float a, float b) {   // v_cvt_pk_bf16_f32
    float2 f; f.x = a; f.y = b;
    __hip_bfloat162 h = __float22bfloat162_rn(f);
    union { __hip_bfloat162 h2; ushort2 u2; } u;
    u.h2 = h;
    return u.u2;
}
__device__ __forceinline__ int swz16(int row, int colbyte) {  // K, V^T tiles
    return row * 128 + ((((colbyte >> 4) ^ (row & 7)) << 4) | (colbyte & 15));
}
__device__ __forceinline__ float fm3(float a, float b, float c) {  // v_max3
    return fmaxf(fmaxf(a, b), c);
}
// max over lanes l, l^16 (resp. ^32): builtin permlane swap (compiler handles
// hazard NOPs + 2-result reg constraints). With both inputs = x the returned
// pair {a',b'} satisfies fmax(a',b') = max(x[l], x[l^16]) in every lane.
__device__ __forceinline__ float plmax16(float x) {
#ifdef HAVE_PLSWAP
    u32x2 r = __builtin_amdgcn_permlane16_swap(__float_as_uint(x),
                                               __float_as_uint(x), false, false);
    return fmaxf(__uint_as_float(r[0]), __uint_as_float(r[1]));
#else
    return fmaxf(x, __shfl_xor(x, 16));
#endif
}
__device__ __forceinline__ float plmax32(float x) {
#ifdef HAVE_PLSWAP
    u32x2 r = __builtin_amdgcn_permlane32_swap(__float_as_uint(x),
                                               __float_as_uint(x), false, false);
    return fmaxf(__uint_as_float(r[0]), __uint_as_float(r[1]));
#else
    return fmaxf(x, __shfl_xor(x, 32));
#endif
}

__global__ __launch_bounds__(512, 4)
void attn_v23(const float* __restrict__ Q, const float* __restrict__ K,
              const float* __restrict__ V, const int* __restrict__ VL,
              float* __restrict__ O) {
    __shared__ ushort KsB[2][KVT * DH];   // swz16 [phys key][d] 16 KB
    __shared__ ushort VtB[2][DH * KVT];   // swz16 [d][key]      16 KB
    __shared__ ushort sched[NB];          // rank -> batch        128 B => 32896

    const int tid = threadIdx.x;
    const int wid = tid >> 6, l = tid & 63, g = l >> 4, a = l & 15;

    // ---- in-kernel stratified-LPT schedule ----
    if (tid < NB) {
        const int ntb = (VL[tid] + KVT - 1) >> 6;
        int r = 0;
        for (int j = 0; j < NB; ++j) {
            const int ntj = (VL[j] + KVT - 1) >> 6;
            r += (int)((ntj > ntb) | ((ntj == ntb) & (j < tid)));
        }
        sched[r] = (ushort)tid;           // rank -> batch (desc nt, tie asc)
    }
    __syncthreads();
    const int xcd   = blockIdx.x & 7;     // HW: block i -> XCD i%8
    const int slot  = blockIdx.x >> 3;    // 0..63 within XCD
    const int qtile = slot & 7;           // 8 q-slots of 128 rows
    const int st    = slot >> 3;          // stratum 0..7
    // pairing perm8={0,1,2,3,7,6,5,4}: CU gets complementary strata
    const int rank  = xcd + ((st < 4) ? st : (11 - st)) * 8;
    const int b     = sched[rank];
    const int qbase = qtile * QT;
    const int valid = VL[b];              // 1..1024
    const int nt = (valid + KVT - 1) >> 6;

    // Hoisted LDS read offsets: same formula serves K and V reads.
    int off8[8];                          // [n][kblk] -> n*2 + kblk
    #pragma unroll
    for (int n = 0; n < 4; ++n)
        #pragma unroll
        for (int kblk = 0; kblk < 2; ++kblk)
            off8[n * 2 + kblk] = swz16(n * 16 + a, kblk * 64 + g * 16);

    // Q fragment (B-operand), pre-scaled by SC2: col=a (q-row), k=32kblk+8g+i
    const float* Qr = Q + ((size_t)b * LQ + qbase + wid * 16 + a) * DH;
    bf8 qa[2];
    #pragma unroll
    for (int kblk = 0; kblk < 2; ++kblk) {
        f4 x = *(const f4*)(Qr + kblk * 32 + g * 8);
        f4 y = *(const f4*)(Qr + kblk * 32 + g * 8 + 4);
        ushort2 c0 = cvt2(x[0] * SC2, x[1] * SC2), c1 = cvt2(x[2] * SC2, x[3] * SC2);
        ushort2 c2 = cvt2(y[0] * SC2, y[1] * SC2), c3 = cvt2(y[2] * SC2, y[3] * SC2);
        qa[kblk][0] = (short)c0.x; qa[kblk][1] = (short)c0.y;
        qa[kblk][2] = (short)c1.x; qa[kblk][3] = (short)c1.y;
        qa[kblk][4] = (short)c2.x; qa[kblk][5] = (short)c2.y;
        qa[kblk][6] = (short)c3.x; qa[kblk][7] = (short)c3.y;
    }
    const bf8 ones = {0x3F80, 0x3F80, 0x3F80, 0x3F80,
                      0x3F80, 0x3F80, 0x3F80, 0x3F80};   // bf16 1.0 x8
    const f4 Z4 = {0.f, 0.f, 0.f, 0.f};  // persistent zero C-operand

    // staging roles: waves 0-3 stage V, waves 4-7 stage K (R16 split)
    const int  rtid  = tid & 255;
    const bool vrole = (wid < 4);
    const int srow = rtid >> 3, sslot = rtid & 7;   // K rows srow, srow+32
    const int vkp  = rtid >> 4, vj = rtid & 15;     // V keys 4vkp.., f4-col vj
    // physical LDS row for K key srow (<32): swap bits 3..4 with bit 2
    const int prow = (srow & 3) | ((srow & 24) >> 1) | ((srow & 4) << 2);
    const f4* Kb4 = (const f4*)(K + (size_t)b * LK * DH);
    const f4* Vb4 = (const f4*)(V + (size_t)b * LK * DH);

    f4 r0, r1, r2, r3;
    auto load_kv = [&](int k0) {
        if (vrole) {
            r0 = Vb4[(k0 + 4 * vkp + 0) * 16 + vj];
            r1 = Vb4[(k0 + 4 * vkp + 1) * 16 + vj];
            r2 = Vb4[(k0 + 4 * vkp + 2) * 16 + vj];
            r3 = Vb4[(k0 + 4 * vkp + 3) * 16 + vj];
        } else {
            r0 = Kb4[(k0 + srow) * 16 + sslot * 2];
            r1 = Kb4[(k0 + srow) * 16 + sslot * 2 + 1];
            r2 = Kb4[(k0 + srow + 32) * 16 + sslot * 2];
            r3 = Kb4[(k0 + srow + 32) * 16 + sslot * 2 + 1];
        }
    };
    auto store_kv = [&](int bs) {
        if (vrole) {
            char* vd = (char*)&VtB[bs][0];
            #pragma unroll
            for (int c = 0; c < 4; ++c) {      // transpose: d = 4*vj+c
                ushort2 a01 = cvt2(r0[c], r1[c]), a23 = cvt2(r2[c], r3[c]);
                u16x4 p = {a01.x, a01.y, a23.x, a23.y};
                *(u16x4*)(vd + swz16(4 * vj + c, vkp * 8)) = p;
            }
        } else {
            char* kd = (char*)&KsB[bs][0];
            {
                ushort2 c0 = cvt2(r0[0], r0[1]), c1 = cvt2(r0[2], r0[3]);
                ushort2 c2 = cvt2(r1[0], r1[1]), c3 = cvt2(r1[2], r1[3]);
                u16x8 w = {c0.x, c0.y, c1.x, c1.y, c2.x, c2.y, c3.x, c3.y};
                *(u16x8*)(kd + swz16(prow, sslot * 16)) = w;
            }
            {
                ushort2 c0 = cvt2(r2[0], r2[1]), c1 = cvt2(r2[2], r2[3]);
                ushort2 c2 = cvt2(r3[0], r3[1]), c3 = cvt2(r3[2], r3[3]);
                u16x8 w = {c0.x, c0.y, c1.x, c1.y, c2.x, c2.y, c3.x, c3.y};
                *(u16x8*)(kd + swz16(prow + 32, sslot * 16)) = w;
            }
        }
    };

    f4 oacc[4];
    #pragma unroll
    for (int n = 0; n < 4; ++n) oacc[n] = f4{0.f, 0.f, 0.f, 0.f};
    f4 lacc = f4{0.f, 0.f, 0.f, 0.f};   // l per q-row 4g+r (epilogue layout)
    float m_run = -NEGF;                // per-lane: q-row = a

    // One tile iteration; bs literal -> LDS bases fold into ds immediates.
    auto tile_iter = [&](int t, const int bs) {
        __syncthreads();                         // buf[bs] ready block-wide
        if (t + 1 < nt) load_kv((t + 1) * KVT);  // issue early...
        __builtin_amdgcn_sched_barrier(0);       // ...keep it early

        // ---- S^T = K Q^T: lane (g,a) holds S[q=a][key=32(n>>1)+4(n&1)+8g+r]
        const char* kd = (const char*)&KsB[bs][0];
        f4 sacc[4];
        __builtin_amdgcn_s_setprio(1);
        #pragma unroll
        for (int n = 0; n < 4; ++n) {
            bf8 kb0 = *(const bf8*)(kd + off8[n * 2 + 0]);
            bf8 kb1 = *(const bf8*)(kd + off8[n * 2 + 1]);
            sacc[n] = __builtin_amdgcn_mfma_f32_16x16x32_bf16(
                kb0, qa[0], Z4, 0, 0, 0);            // C = zero (no init movs)
            sacc[n] = __builtin_amdgcn_mfma_f32_16x16x32_bf16(
                kb1, qa[1], sacc[n], 0, 0, 0);
        }
        __builtin_amdgcn_s_setprio(0);

        // ---- mask in place ----
        const int kmax = valid - t * KVT;
        if (kmax < KVT) {
            #pragma unroll
            for (int n = 0; n < 4; ++n)
                #pragma unroll
                for (int r = 0; r < 4; ++r)
                    if (32 * (n >> 1) + 4 * (n & 1) + 8 * g + r >= kmax)
                        sacc[n][r] = -NEGF;
        }

        // ---- softmax max: 3-ary tree (v_max3) + builtin permlane swaps ----
        float t0 = fm3(sacc[0][0], sacc[0][1], sacc[0][2]);
        float t1 = fm3(sacc[0][3], sacc[1][0], sacc[1][1]);
        float t2 = fm3(sacc[1][2], sacc[1][3], sacc[2][0]);
        float t3 = fm3(sacc[2][1], sacc[2][2], sacc[2][3]);
        float t4 = fm3(sacc[3][0], sacc[3][1], sacc[3][2]);
        float tm = fmaxf(fm3(t0, t1, t2), fm3(t3, t4, sacc[3][3]));
        tm = plmax16(tm);                     // == fmax(tm, shfl_xor(tm,16))
        tm = plmax32(tm);                     // == fmax(tm, shfl_xor(tm,32))

        float rs_ = 1.0f;                     // T13 defer-max
        const bool skip = __all(tm <= m_run + THR);
        if (!skip) {
            const float mnew = fmaxf(m_run, tm);
            rs_ = __builtin_exp2f(m_run - mnew);   // tile0: exp2(-inf)=0
            m_run = mnew;
        }
        if (!skip) {   // rescale O,l rows (q=4g+r)
            float rr[4];
            #pragma unroll
            for (int r = 0; r < 4; ++r) rr[r] = __shfl(rs_, 4 * g + r);
            #pragma unroll
            for (int n = 0; n < 4; ++n)
                #pragma unroll
                for (int r = 0; r < 4; ++r) oacc[n][r] *= rr[r];
            #pragma unroll
            for (int r = 0; r < 4; ++r) lacc[r] *= rr[r];
        }

        // ---- O += P V ; l += P * ones  (exp2->cvt->MFMA fused per kblk) ----
        const char* vd = (const char*)&VtB[bs][0];
        __builtin_amdgcn_s_setprio(1);
        #pragma unroll
        for (int kblk = 0; kblk < 2; ++kblk) {
            float p0[4], p1[4];
            #pragma unroll
            for (int r = 0; r < 4; ++r) {
                p0[r] = __builtin_exp2f(sacc[2 * kblk][r] - m_run);     // masked->0
                p1[r] = __builtin_exp2f(sacc[2 * kblk + 1][r] - m_run);
            }
            ushort2 w0 = cvt2(p0[0], p0[1]), w1 = cvt2(p0[2], p0[3]);
            ushort2 w2 = cvt2(p1[0], p1[1]), w3 = cvt2(p1[2], p1[3]);
            bf8 pa = {(short)w0.x, (short)w0.y, (short)w1.x, (short)w1.y,
                      (short)w2.x, (short)w2.y, (short)w3.x, (short)w3.y};
            #pragma unroll
            for (int n = 0; n < 4; ++n) {
                bf8 vb_ = *(const bf8*)(vd + off8[n * 2 + kblk]);
                oacc[n] = __builtin_amdgcn_mfma_f32_16x16x32_bf16(
                    pa, vb_, oacc[n], 0, 0, 0);
            }
            lacc = __builtin_amdgcn_mfma_f32_16x16x32_bf16(pa, ones, lacc, 0, 0, 0);
        }
        __builtin_amdgcn_s_setprio(0);

        if (t + 1 < nt) store_kv(bs ^ 1);   // post-compute, pre-next-barrier
    };

    load_kv(0);
    store_kv(0);
    for (int t = 0; t < nt; t += 2) {       // unroll-2: bs literal
        tile_iter(t, 0);
        if (t + 1 < nt) tile_iter(t + 1, 1);
    }

    // ---- epilogue: O[q=4g+r][d=16n+a] / l (lacc already row-layout) ----
    float iv[4];
    #pragma unroll
    for (int r = 0; r < 4; ++r) iv[r] = 1.0f / lacc[r];
    float* Ob = O + ((size_t)b * LQ + qbase + wid * 16) * DH;
    #pragma unroll
    for (int n = 0; n < 4; ++n)
        #pragma unroll
        for (int r = 0; r < 4; ++r)
            Ob[(size_t)(4 * g + r) * DH + 16 * n + a] = oacc[n][r] * iv[r];
}

extern "C" void kernel_launch(void* const* d_in, const int* in_sizes, int n_in,
                              void* d_out, int out_size, void* d_ws, size_t ws_size,
                              hipStream_t stream) {
    const float* Q  = (const float*)d_in[0];
    const float* K  = (const float*)d_in[1];
    const float* V  = (const float*)d_in[2];
    const int*   VL = (const int*)d_in[3];
    float* O = (float*)d_out;

    attn_v23<<<NITEMS, 512, 0, stream>>>(Q, K, V, VL, O);
}